// Round 1
// baseline (211.705 us; speedup 1.0000x reference)
//
#include <hip/hip_runtime.h>

// out[b,i,j] = x[b, k(min(i,j), max(i,j))], n=512, D=n(n+1)/2=131328
// k(r,c) = r*n - r*(r-1)/2 + (c-r) = r*(1025-r)/2 + (c-r)  for n=512

__global__ __launch_bounds__(256) void spd_unvec_kernel(const float* __restrict__ x,
                                                        float* __restrict__ out) {
    constexpr int N = 512;
    constexpr int D = 131328;          // N*(N+1)/2
    // one float4 of output per thread; 128 float4 per row of 512
    int v  = blockIdx.x * 256 + threadIdx.x;   // float4 index into out
    int j0 = (v & 127) << 2;                   // starting column
    int rowlin = v >> 7;                       // b*512 + i
    int i = rowlin & (N - 1);
    int b = rowlin >> 9;

    const float* __restrict__ xb = x + (size_t)b * D;

    float4 o;
    float* op = reinterpret_cast<float*>(&o);
#pragma unroll
    for (int t = 0; t < 4; ++t) {
        int j = j0 + t;
        int r = (i < j) ? i : j;
        int c = (i < j) ? j : i;
        int k = ((r * (2 * N + 1 - r)) >> 1) + (c - r);  // r*(1025-r)/2 + (c-r)
        op[t] = xb[k];
    }
    reinterpret_cast<float4*>(out)[v] = o;
}

extern "C" void kernel_launch(void* const* d_in, const int* in_sizes, int n_in,
                              void* d_out, int out_size, void* d_ws, size_t ws_size,
                              hipStream_t stream) {
    const float* x = (const float*)d_in[0];
    float* out = (float*)d_out;
    // total float4 elements: 256 * 512 * 512 / 4 = 16,777,216 -> 65536 blocks of 256
    int total_vec4 = out_size / 4;
    int blocks = total_vec4 / 256;
    spd_unvec_kernel<<<blocks, 256, 0, stream>>>(x, out);
}

// Round 2
// 81.375 us; speedup vs baseline: 2.6016x; 2.6016x over previous
//
#include <hip/hip_runtime.h>

// out[b,i,j] = x[b, k(min(i,j), max(i,j))], n=512, D=n(n+1)/2=131328
// k(r,c) = r*(2N+1-r)/2 + (c-r)
//
// Tiled: one block per (b, upper-tri 64x64 tile). Load packed tile rows
// (contiguous per row) -> LDS, write direct tile + transposed tile with
// coalesced float4 stores. Each x element fetched from HBM exactly once.

constexpr int N = 512;
constexpr int D = 131328;          // N*(N+1)/2
constexpr int T = 64;              // tile dim
constexpr int NT = N / T;          // 8
constexpr int NTILES = NT * (NT + 1) / 2;  // 36

__global__ __launch_bounds__(256) void spd_unvec_tiled(const float* __restrict__ x,
                                                       float* __restrict__ out) {
    __shared__ float lds[T][T + 1];   // +1 pad: transpose reads conflict-free

    int u = blockIdx.x % NTILES;
    int b = blockIdx.x / NTILES;
    int ti = 0;
    while (u >= NT - ti) { u -= NT - ti; ++ti; }   // uniform scalar loop, <=8 iters
    int tj = ti + u;

    const int i0 = ti * T;
    const int c0 = tj * T;
    const float* __restrict__ xb = x + (size_t)b * D;
    float* __restrict__ ob = out + (size_t)b * N * N;

    const int t = threadIdx.x;

    // ---- load: 16 iters x (4 rows x 64 cols), contiguous 64-float rows ----
    {
        int col = t & 63;
        int rq  = t >> 6;
#pragma unroll
        for (int it = 0; it < 16; ++it) {
            int row = it * 4 + rq;
            int r = i0 + row, c = c0 + col;
            int rm = r < c ? r : c;             // only differs on diagonal tiles
            int cm = r < c ? c : r;
            int k = ((rm * (2 * N + 1 - rm)) >> 1) + (cm - rm);
            lds[row][col] = xb[k];
        }
    }
    __syncthreads();

    const int c4 = (t & 15) << 2;
    const int rh = t >> 4;

    // ---- direct tile write: out[i0+row][c0 + c] ----
#pragma unroll
    for (int it = 0; it < 4; ++it) {
        int row = it * 16 + rh;
        float4 v;
        v.x = lds[row][c4 + 0];
        v.y = lds[row][c4 + 1];
        v.z = lds[row][c4 + 2];
        v.w = lds[row][c4 + 3];
        *reinterpret_cast<float4*>(&ob[(size_t)(i0 + row) * N + c0 + c4]) = v;
    }

    // ---- transposed tile write: out[c0+row][i0 + c] = lds[c][row] ----
    if (ti != tj) {
#pragma unroll
        for (int it = 0; it < 4; ++it) {
            int row = it * 16 + rh;
            float4 v;
            v.x = lds[c4 + 0][row];
            v.y = lds[c4 + 1][row];
            v.z = lds[c4 + 2][row];
            v.w = lds[c4 + 3][row];
            *reinterpret_cast<float4*>(&ob[(size_t)(c0 + row) * N + i0 + c4]) = v;
        }
    }
}

extern "C" void kernel_launch(void* const* d_in, const int* in_sizes, int n_in,
                              void* d_out, int out_size, void* d_ws, size_t ws_size,
                              hipStream_t stream) {
    const float* x = (const float*)d_in[0];
    float* out = (float*)d_out;
    int B = in_sizes[0] / D;                 // 256
    int blocks = B * NTILES;                 // 9216
    spd_unvec_tiled<<<blocks, 256, 0, stream>>>(x, out);
}

// Round 4
// 61.731 us; speedup vs baseline: 3.4295x; 1.3182x over previous
//
#include <hip/hip_runtime.h>

// out[b,i,j] = x[b, k(min(i,j), max(i,j))], n=512, D=n(n+1)/2=131328
// k(r,c) = r*(2N+1-r)/2 + (c-r)
//
// Tiled: one block per (b, upper-tri 64x64 tile). Load packed tile rows
// (contiguous per row) -> LDS, write direct tile + transposed tile with
// coalesced float4 nontemporal stores.
//
// R4: same as R3 but nontemporal stores use a native ext_vector_type float4
// (HIP_vector_type is rejected by __builtin_nontemporal_store).

typedef float f32x4 __attribute__((ext_vector_type(4)));

constexpr int N = 512;
constexpr int D = 131328;                  // N*(N+1)/2
constexpr int T = 64;                      // tile dim
constexpr int NT = N / T;                  // 8
constexpr int NTILES = NT * (NT + 1) / 2;  // 36
constexpr int NXCD = 8;

__global__ __launch_bounds__(256) void spd_unvec_tiled(const float* __restrict__ x,
                                                       float* __restrict__ out,
                                                       int chunk) {
    __shared__ float lds[T][T + 1];   // +1 pad: transpose reads conflict-free

    // XCD swizzle: hw XCD = blockIdx.x % 8; give each XCD a contiguous
    // logical range so same-batch tiles share that XCD's L2.
    int L = (blockIdx.x % NXCD) * chunk + blockIdx.x / NXCD;

    int u = L % NTILES;
    int b = L / NTILES;
    int ti = 0;
    while (u >= NT - ti) { u -= NT - ti; ++ti; }   // uniform scalar loop, <=8 iters
    int tj = ti + u;

    const int i0 = ti * T;
    const int c0 = tj * T;
    const float* __restrict__ xb = x + (size_t)b * D;
    float* __restrict__ ob = out + (size_t)b * N * N;

    const int t = threadIdx.x;

    // ---- load: 16 iters x (4 rows x 64 cols), contiguous 64-float rows ----
    {
        int col = t & 63;
        int rq  = t >> 6;
#pragma unroll
        for (int it = 0; it < 16; ++it) {
            int row = it * 4 + rq;
            int r = i0 + row, c = c0 + col;
            int rm = r < c ? r : c;             // only differs on diagonal tiles
            int cm = r < c ? c : r;
            int k = ((rm * (2 * N + 1 - rm)) >> 1) + (cm - rm);
            lds[row][col] = xb[k];
        }
    }
    __syncthreads();

    const int c4 = (t & 15) << 2;
    const int rh = t >> 4;

    // ---- direct tile write: out[i0+row][c0 + c] ----
#pragma unroll
    for (int it = 0; it < 4; ++it) {
        int row = it * 16 + rh;
        f32x4 v;
        v.x = lds[row][c4 + 0];
        v.y = lds[row][c4 + 1];
        v.z = lds[row][c4 + 2];
        v.w = lds[row][c4 + 3];
        __builtin_nontemporal_store(
            v, reinterpret_cast<f32x4*>(&ob[(size_t)(i0 + row) * N + c0 + c4]));
    }

    // ---- transposed tile write: out[c0+row][i0 + c] = lds[c][row] ----
    if (ti != tj) {
#pragma unroll
        for (int it = 0; it < 4; ++it) {
            int row = it * 16 + rh;
            f32x4 v;
            v.x = lds[c4 + 0][row];
            v.y = lds[c4 + 1][row];
            v.z = lds[c4 + 2][row];
            v.w = lds[c4 + 3][row];
            __builtin_nontemporal_store(
                v, reinterpret_cast<f32x4*>(&ob[(size_t)(c0 + row) * N + i0 + c4]));
        }
    }
}

extern "C" void kernel_launch(void* const* d_in, const int* in_sizes, int n_in,
                              void* d_out, int out_size, void* d_ws, size_t ws_size,
                              hipStream_t stream) {
    const float* x = (const float*)d_in[0];
    float* out = (float*)d_out;
    int B = in_sizes[0] / D;                 // 256
    int blocks = B * NTILES;                 // 9216, divisible by 8
    int chunk = blocks / NXCD;               // 1152
    spd_unvec_tiled<<<blocks, 256, 0, stream>>>(x, out, chunk);
}